// Round 2
// baseline (110.148 us; speedup 1.0000x reference)
//
#include <hip/hip_runtime.h>

typedef _Float16 f16x8 __attribute__((ext_vector_type(8)));
typedef float f32x16 __attribute__((ext_vector_type(16)));

#define TRUNC_VAL 2.0f
#define NSEG 32            // target segments
#define WPB 4              // waves per block
#define BPT 8              // query (B) tiles per wave
#define SEGB (NSEG / WPB)  // P stripes = grid.y = 8

// ---------------------------------------------------------------------------
// Pack kernel: builds MFMA fragment panels + zeroes the election counters
// (workspace is re-poisoned by the harness each iteration, so the counters
// MUST be reset here; pack is stream-ordered before the main kernel).
//  A/B panels for v_mfma_f32_32x32x16_f16, lane l of tile t at frag[t*64+l].
//  K-slot usage (hi/lo fp16 split, ~22-bit effective precision):
//    A (target j): [xh yh zh | xh yh zh | xl yl zl | wh wl | 0...]  w=-0.5*||y||^2
//    B (query  i): [xh yh zh | xl yl zl | xh yh zh | 1  1  | 0...]
//  => dot ~= q.y - 0.5||y||^2   (verified: absmax 0.0 in prior session)
// ---------------------------------------------------------------------------
__global__ void pack_kernel(const float* __restrict__ fw, const float* __restrict__ bwv,
                            const float* __restrict__ p0, const float* __restrict__ p1,
                            f16x8* __restrict__ Afw, f16x8* __restrict__ Abw,
                            f16x8* __restrict__ Bfw, f16x8* __restrict__ Bbw,
                            int* __restrict__ cnt, int* __restrict__ gcnt,
                            int N, int NT, int ncol) {
    int i = blockIdx.x * blockDim.x + threadIdx.x;

    // reset election counters (re-poisoned workspace!)
    if (i < 2 * ncol) cnt[i] = 0;
    if (i == 2 * ncol) *gcnt = 0;

    int per_panel = NT * 64;
    int total = 4 * per_panel;
    if (i >= total) return;
    int panel = i / per_panel;
    int rem   = i - panel * per_panel;
    int tile  = rem >> 6;
    int lane  = rem & 63;
    int idx   = tile * 32 + (lane & 31);
    int khi   = (lane >> 5) * 8;

    float x, y, z;
    if (panel == 0)      { x = p1[3*idx]; y = p1[3*idx+1]; z = p1[3*idx+2]; }
    else if (panel == 1) { x = p0[3*idx]; y = p0[3*idx+1]; z = p0[3*idx+2]; }
    else {
        x = p0[3*idx]   + fw[3*idx];
        y = p0[3*idx+1] + fw[3*idx+1];
        z = p0[3*idx+2] + fw[3*idx+2];
        if (panel == 3) { x -= bwv[3*idx]; y -= bwv[3*idx+1]; z -= bwv[3*idx+2]; }
    }
    _Float16 xh = (_Float16)x, yh = (_Float16)y, zh = (_Float16)z;
    _Float16 xl = (_Float16)(x - (float)xh);
    _Float16 yl = (_Float16)(y - (float)yh);
    _Float16 zl = (_Float16)(z - (float)zh);

    _Float16 s[16];
    #pragma unroll
    for (int k = 0; k < 16; ++k) s[k] = (_Float16)0.0f;
    if (panel < 2) {   // A panel (targets)
        float w = -0.5f * (x*x + y*y + z*z);
        _Float16 wh = (_Float16)w, wl = (_Float16)(w - (float)wh);
        s[0]=xh; s[1]=yh; s[2]=zh;
        s[3]=xh; s[4]=yh; s[5]=zh;
        s[6]=xl; s[7]=yl; s[8]=zl;
        s[9]=wh; s[10]=wl;
    } else {           // B panel (queries)
        s[0]=xh; s[1]=yh; s[2]=zh;
        s[3]=xl; s[4]=yl; s[5]=zl;
        s[6]=xh; s[7]=yh; s[8]=zh;
        s[9]=(_Float16)1.0f; s[10]=(_Float16)1.0f;
    }
    f16x8 o;
    #pragma unroll
    for (int t = 0; t < 8; ++t) o[t] = s[khi + t];
    f16x8* dst = (panel == 0) ? Afw : (panel == 1) ? Abw : (panel == 2) ? Bfw : Bbw;
    dst[tile * 64 + lane] = o;
}

// ---------------------------------------------------------------------------
// Main kernel: chamfer MFMA loop (unchanged) + fused reduction.
//  - block-level fold of the 4 waves' segment maxima via LDS -> 8 P stripes
//  - last block per (col,dir) (counter zeroed by pack, so the firing block
//    really is the 8th/last arriver) computes the truncated chamfer for its
//    256 queries and a block partial
//  - last block overall sums the 128 partials and OVERWRITES out[0]
// ---------------------------------------------------------------------------
__global__ __launch_bounds__(64 * WPB) void chamfer_mfma_kernel(
    const f16x8* __restrict__ Afw, const f16x8* __restrict__ Bfw, float* __restrict__ Pfw,
    const f16x8* __restrict__ Abw, const f16x8* __restrict__ Bbw, float* __restrict__ Pbw,
    const float* __restrict__ fwv, const float* __restrict__ bwv, const float* __restrict__ p0,
    float* __restrict__ part2, int* __restrict__ cnt, int* __restrict__ gcnt,
    float* __restrict__ out, int N, int tilesPerSeg, float inv) {
    __shared__ float sM[WPB][32 * BPT];
    __shared__ float wsum[WPB];
    __shared__ int sFlag;
    __shared__ int sFinal;

    int tid  = threadIdx.x;
    int lane = tid & 63;
    int wave = tid >> 6;
    int col  = blockIdx.x;                 // query column: BPT*32 = 256 queries
    int seg  = blockIdx.y * WPB + wave;    // target segment
    int z    = blockIdx.z;
    const f16x8* __restrict__ A = z ? Abw : Afw;
    const f16x8* __restrict__ B = z ? Bbw : Bfw;
    float* __restrict__ P = z ? Pbw : Pfw;

    f16x8 b[BPT];
    float m[BPT][4];
    #pragma unroll
    for (int c = 0; c < BPT; ++c) {
        b[c] = B[(col * BPT + c) * 64 + lane];
        #pragma unroll
        for (int p = 0; p < 4; ++p) m[c][p] = -3.0e38f;
    }

    const f32x16 zero = {};
    const f16x8* Ap = A + (size_t)seg * tilesPerSeg * 64 + lane;

    f16x8 a = Ap[0];
    for (int t = 0; t < tilesPerSeg; ++t) {
        f16x8 a_cur = a;
        int tn = (t + 1 < tilesPerSeg) ? t + 1 : t;
        a = Ap[tn * 64];                       // prefetch next A-frag
        #pragma unroll
        for (int c = 0; c < BPT; ++c) {
            f32x16 d = __builtin_amdgcn_mfma_f32_32x32x16_f16(a_cur, b[c], zero, 0, 0, 0);
            #pragma unroll
            for (int p = 0; p < 4; ++p) {
                m[c][p] = fmaxf(fmaxf(m[c][p], d[4*p  ]), d[4*p+1]);   // v_max3
                m[c][p] = fmaxf(fmaxf(m[c][p], d[4*p+2]), d[4*p+3]);   // v_max3
            }
        }
    }

    // --- fold the block's 4 segments through LDS, write one P stripe ---
    #pragma unroll
    for (int c = 0; c < BPT; ++c) {
        float v = fmaxf(fmaxf(m[c][0], m[c][1]), fmaxf(m[c][2], m[c][3]));
        v = fmaxf(v, __shfl_xor(v, 32, 64));   // fold the two row-halves
        if (lane < 32) sM[wave][c * 32 + lane] = v;
    }
    __syncthreads();
    float mv4 = fmaxf(fmaxf(sM[0][tid], sM[1][tid]), fmaxf(sM[2][tid], sM[3][tid]));
    int i = col * (32 * BPT) + tid;            // query index
    P[(size_t)blockIdx.y * N + i] = mv4;

    // --- release our stripe, elect the last block for this (col, dir) ---
    __threadfence();
    __syncthreads();
    if (tid == 0) {
        int old = atomicAdd(&cnt[z * gridDim.x + col], 1);
        sFlag = (old == SEGB - 1) ? 1 : 0;     // counter zeroed by pack
    }
    __syncthreads();
    if (!sFlag) return;

    // --- fused reduce: 256 queries of this column ---
    __threadfence();                           // acquire other stripes
    float qx = p0[3*i]   + fwv[3*i];
    float qy = p0[3*i+1] + fwv[3*i+1];
    float qz = p0[3*i+2] + fwv[3*i+2];
    if (z) { qx -= bwv[3*i]; qy -= bwv[3*i+1]; qz -= bwv[3*i+2]; }
    float q2 = qx*qx + qy*qy + qz*qz;
    float mv = P[i];
    #pragma unroll
    for (int s = 1; s < SEGB; ++s) mv = fmaxf(mv, P[(size_t)s * N + i]);
    float d2 = fmaf(-2.0f, mv, q2);            // ||q||^2 - 2*max = min sq dist
    d2 = fmaxf(d2, 0.0f);
    float cv = fminf(d2, TRUNC_VAL);
    #pragma unroll
    for (int off = 32; off > 0; off >>= 1) cv += __shfl_down(cv, off, 64);
    if (lane == 0) wsum[wave] = cv;
    __syncthreads();
    int tot = 2 * gridDim.x;                   // 128 column-partials
    if (tid == 0) {
        part2[z * gridDim.x + col] = (wsum[0] + wsum[1] + wsum[2] + wsum[3]) * inv;
        __threadfence();
        int o2 = atomicAdd(gcnt, 1);
        sFinal = (o2 == tot - 1) ? 1 : 0;      // counter zeroed by pack
    }
    __syncthreads();
    if (!sFinal) return;

    // --- last block overall: sum the 128 partials, overwrite out[0] ---
    __threadfence();
    float v = (tid < tot) ? part2[tid] : 0.0f;
    #pragma unroll
    for (int off = 32; off > 0; off >>= 1) v += __shfl_down(v, off, 64);
    if (lane == 0) wsum[wave] = v;
    __syncthreads();
    if (tid == 0) out[0] = wsum[0] + wsum[1] + wsum[2] + wsum[3];
}

extern "C" void kernel_launch(void* const* d_in, const int* in_sizes, int n_in,
                              void* d_out, int out_size, void* d_ws, size_t ws_size,
                              hipStream_t stream) {
    const float* fw  = (const float*)d_in[0];  // fw_flow_pred [N,3]
    const float* bwv = (const float*)d_in[1];  // bw_flow_pred [N,3]
    const float* p0  = (const float*)d_in[2];  // pcl_0 [N,3]
    const float* p1  = (const float*)d_in[3];  // pcl_1 [M,3]
    int N = in_sizes[0] / 3;                   // 16384; M == N for this problem
    int NT = N / 32;                           // 512 target/query tiles
    int tilesPerSeg = NT / NSEG;               // 16
    int ncol = N / (32 * BPT);                 // 64 query columns

    float* out = (float*)d_out;
    char* w = (char*)d_ws;
    f16x8* Afw  = (f16x8*)w;                   w += (size_t)NT * 64 * 16;
    f16x8* Abw  = (f16x8*)w;                   w += (size_t)NT * 64 * 16;
    f16x8* Bfw  = (f16x8*)w;                   w += (size_t)NT * 64 * 16;
    f16x8* Bbw  = (f16x8*)w;                   w += (size_t)NT * 64 * 16;
    float* Pfw  = (float*)w;                   w += (size_t)SEGB * N * 4;
    float* Pbw  = (float*)w;                   w += (size_t)SEGB * N * 4;
    float* part2 = (float*)w;                  w += (size_t)2 * ncol * 4;
    int*   cnt   = (int*)w;                    w += (size_t)2 * ncol * 4;
    int*   gcnt  = (int*)w;

    int pack_threads = 4 * NT * 64;
    pack_kernel<<<(pack_threads + 255) / 256, 256, 0, stream>>>(
        fw, bwv, p0, p1, Afw, Abw, Bfw, Bbw, cnt, gcnt, N, NT, ncol);

    dim3 grid(ncol, SEGB, 2);
    chamfer_mfma_kernel<<<grid, 64 * WPB, 0, stream>>>(
        Afw, Bfw, Pfw, Abw, Bbw, Pbw, fw, bwv, p0,
        part2, cnt, gcnt, out, N, tilesPerSeg, 1.0f / N);
}

// Round 3
// 40.038 us; speedup vs baseline: 2.7511x; 2.7511x over previous
//
#include <hip/hip_runtime.h>

typedef _Float16 f16x8 __attribute__((ext_vector_type(8)));
typedef float f32x16 __attribute__((ext_vector_type(16)));

#define TRUNC_VAL 2.0f
#define NSEG 32    // target segments
#define WPB 4      // waves per block
#define BPT 8      // query (B) tiles per wave: 8 MFMAs per A-frag load

// ---------------------------------------------------------------------------
// Pack kernel (identical to the verified 39.9us baseline).
//  - qfw/qbw: float4 (x,y,z,||q||^2) per query, fp32, for the finalize step.
//  - A panels (targets) / B panels (queries): MFMA fragments for
//    v_mfma_f32_32x32x16_f16, lane l of tile t reads its 8 halves at
//    frag[t*64 + l].  Lane mapping: row/col = l&31, k = 8*(l>>5)+i.
//    K-slot usage (hi/lo fp16 split, ~22-bit effective precision):
//      A (target j): [xh yh zh | xh yh zh | xl yl zl | wh wl | 0...]  w=-0.5*||y||^2
//      B (query  i): [xh yh zh | xl yl zl | xh yh zh | 1  1  | 0...]
//    => dot = q.y - 0.5||y||^2   (verified: absmax 0.0)
// ---------------------------------------------------------------------------
__global__ void pack_kernel(const float* __restrict__ fw, const float* __restrict__ bwv,
                            const float* __restrict__ p0, const float* __restrict__ p1,
                            float4* __restrict__ qfw, float4* __restrict__ qbw,
                            f16x8* __restrict__ Afw, f16x8* __restrict__ Abw,
                            f16x8* __restrict__ Bfw, f16x8* __restrict__ Bbw,
                            float* __restrict__ out, int N, int NT) {
    int i = blockIdx.x * blockDim.x + threadIdx.x;
    if (i == 0) out[0] = 0.0f;
    if (i < N) {
        float px = p0[3*i], py = p0[3*i+1], pz = p0[3*i+2];
        float qx = px + fw[3*i], qy = py + fw[3*i+1], qz = pz + fw[3*i+2];
        qfw[i] = make_float4(qx, qy, qz, qx*qx + qy*qy + qz*qz);
        float bx = qx - bwv[3*i], by = qy - bwv[3*i+1], bz = qz - bwv[3*i+2];
        qbw[i] = make_float4(bx, by, bz, bx*bx + by*by + bz*bz);
    }
    int per_panel = NT * 64;
    int total = 4 * per_panel;
    if (i < total) {
        int panel = i / per_panel;
        int rem   = i - panel * per_panel;
        int tile  = rem >> 6;
        int lane  = rem & 63;
        int idx   = tile * 32 + (lane & 31);
        int khi   = (lane >> 5) * 8;

        float x, y, z;
        if (panel == 0)      { x = p1[3*idx]; y = p1[3*idx+1]; z = p1[3*idx+2]; }
        else if (panel == 1) { x = p0[3*idx]; y = p0[3*idx+1]; z = p0[3*idx+2]; }
        else {
            x = p0[3*idx]   + fw[3*idx];
            y = p0[3*idx+1] + fw[3*idx+1];
            z = p0[3*idx+2] + fw[3*idx+2];
            if (panel == 3) { x -= bwv[3*idx]; y -= bwv[3*idx+1]; z -= bwv[3*idx+2]; }
        }
        _Float16 xh = (_Float16)x, yh = (_Float16)y, zh = (_Float16)z;
        _Float16 xl = (_Float16)(x - (float)xh);
        _Float16 yl = (_Float16)(y - (float)yh);
        _Float16 zl = (_Float16)(z - (float)zh);

        _Float16 s[16];
        #pragma unroll
        for (int k = 0; k < 16; ++k) s[k] = (_Float16)0.0f;
        if (panel < 2) {   // A panel (targets)
            float w = -0.5f * (x*x + y*y + z*z);
            _Float16 wh = (_Float16)w, wl = (_Float16)(w - (float)wh);
            s[0]=xh; s[1]=yh; s[2]=zh;
            s[3]=xh; s[4]=yh; s[5]=zh;
            s[6]=xl; s[7]=yl; s[8]=zl;
            s[9]=wh; s[10]=wl;
        } else {           // B panel (queries)
            s[0]=xh; s[1]=yh; s[2]=zh;
            s[3]=xl; s[4]=yl; s[5]=zl;
            s[6]=xh; s[7]=yh; s[8]=zh;
            s[9]=(_Float16)1.0f; s[10]=(_Float16)1.0f;
        }
        f16x8 o;
        #pragma unroll
        for (int t = 0; t < 8; ++t) o[t] = s[khi + t];
        f16x8* dst = (panel == 0) ? Afw : (panel == 1) ? Abw : (panel == 2) ? Bfw : Bbw;
        dst[tile * 64 + lane] = o;
    }
}

// ---------------------------------------------------------------------------
// Main kernel. Two latency changes vs the 39.9us baseline (numerics identical):
//  1. All WPB waves of a block share ONE target segment (col varies per wave,
//     seg = blockIdx.y): the 16KB A-segment stream fits and stays in the CU's
//     32KB L1, so A-frag loads are L1 hits instead of 4 competing L2 streams.
//  2. A-frag prefetch is 2-deep (a0/a1 ping-pong) to cover the cold-miss
//     latency (~2 loop bodies x 4 waves of issue).
// NO device-scope fences anywhere (R2 lesson: per-block __threadfence L2
// flushes cost 3x more than a kernel boundary).
// ---------------------------------------------------------------------------
__global__ __launch_bounds__(64 * WPB) void chamfer_mfma_kernel(
    const f16x8* __restrict__ Afw, const f16x8* __restrict__ Bfw, float* __restrict__ Pfw,
    const f16x8* __restrict__ Abw, const f16x8* __restrict__ Bbw, float* __restrict__ Pbw,
    int N, int tilesPerSeg) {
    int lane = threadIdx.x & 63;
    int wave = threadIdx.x >> 6;
    int col  = blockIdx.x * WPB + wave;    // query column: BPT*32 = 256 queries
    int seg  = blockIdx.y;                 // target segment (shared by block)
    const f16x8* __restrict__ A;
    const f16x8* __restrict__ B;
    float* __restrict__ P;
    if (blockIdx.z == 0) { A = Afw; B = Bfw; P = Pfw; }
    else                 { A = Abw; B = Bbw; P = Pbw; }

    f16x8 b[BPT];
    float m[BPT][4];
    #pragma unroll
    for (int c = 0; c < BPT; ++c) {
        b[c] = B[(col * BPT + c) * 64 + lane];
        #pragma unroll
        for (int p = 0; p < 4; ++p) m[c][p] = -3.0e38f;
    }

    const f32x16 zero = {};
    const f16x8* Ap = A + (size_t)seg * tilesPerSeg * 64 + lane;

    f16x8 a0 = Ap[0];
    f16x8 a1 = Ap[64];                         // tilesPerSeg >= 2 always (16)
    for (int t = 0; t < tilesPerSeg; ++t) {
        f16x8 a_cur = a0;
        a0 = a1;
        int tn = (t + 2 < tilesPerSeg) ? t + 2 : tilesPerSeg - 1;
        a1 = Ap[tn * 64];                      // prefetch 2 tiles ahead
        #pragma unroll
        for (int c = 0; c < BPT; ++c) {
            f32x16 d = __builtin_amdgcn_mfma_f32_32x32x16_f16(a_cur, b[c], zero, 0, 0, 0);
            #pragma unroll
            for (int p = 0; p < 4; ++p) {
                m[c][p] = fmaxf(fmaxf(m[c][p], d[4*p  ]), d[4*p+1]);   // v_max3
                m[c][p] = fmaxf(fmaxf(m[c][p], d[4*p+2]), d[4*p+3]);   // v_max3
            }
        }
    }

    #pragma unroll
    for (int c = 0; c < BPT; ++c) {
        float v = fmaxf(fmaxf(m[c][0], m[c][1]), fmaxf(m[c][2], m[c][3]));
        v = fmaxf(v, __shfl_xor(v, 32, 64));   // fold the two row-halves
        if (lane < 32) P[(size_t)seg * N + col * (32 * BPT) + c * 32 + lane] = v;
    }
}

// ---------------------------------------------------------------------------
// Combine segment maxima, form truncated chamfer per query, mean-reduce.
// (identical to the verified baseline)
// ---------------------------------------------------------------------------
__global__ __launch_bounds__(256) void reduce_kernel(
    const float4* __restrict__ qfw, const float* __restrict__ pfw,
    const float4* __restrict__ qbw, const float* __restrict__ pbw,
    float* __restrict__ out, int N, float inv) {
    const float4* __restrict__ q4;
    const float* __restrict__ part;
    if (blockIdx.z == 0) { q4 = qfw; part = pfw; }
    else                 { q4 = qbw; part = pbw; }

    int i = blockIdx.x * blockDim.x + threadIdx.x;
    float c = 0.0f;
    if (i < N) {
        float mv = -3.0e38f;
        #pragma unroll
        for (int s = 0; s < NSEG; ++s) mv = fmaxf(mv, part[(size_t)s * N + i]);
        float d2 = fmaf(-2.0f, mv, q4[i].w);   // ||q||^2 - 2*max = min squared dist
        d2 = fmaxf(d2, 0.0f);
        c = fminf(d2, TRUNC_VAL);
    }
    #pragma unroll
    for (int off = 32; off > 0; off >>= 1) c += __shfl_down(c, off, 64);
    __shared__ float wsum[256 / 64];
    int lane = threadIdx.x & 63, wid = threadIdx.x >> 6;
    if (lane == 0) wsum[wid] = c;
    __syncthreads();
    if (threadIdx.x == 0) {
        float s = 0.0f;
        #pragma unroll
        for (int w = 0; w < 256 / 64; ++w) s += wsum[w];
        atomicAdd(out, s * inv);
    }
}

extern "C" void kernel_launch(void* const* d_in, const int* in_sizes, int n_in,
                              void* d_out, int out_size, void* d_ws, size_t ws_size,
                              hipStream_t stream) {
    const float* fw  = (const float*)d_in[0];  // fw_flow_pred [N,3]
    const float* bwv = (const float*)d_in[1];  // bw_flow_pred [N,3]
    const float* p0  = (const float*)d_in[2];  // pcl_0 [N,3]
    const float* p1  = (const float*)d_in[3];  // pcl_1 [M,3]
    int N = in_sizes[0] / 3;                   // 16384; M == N for this problem
    int NT = N / 32;                           // 512 target/query tiles
    int tilesPerSeg = NT / NSEG;               // 16
    int ncol = N / (32 * BPT);                 // 64 query columns

    float* out = (float*)d_out;
    char* w = (char*)d_ws;
    float4* qfw = (float4*)w;                      w += (size_t)N * 16;
    float4* qbw = (float4*)w;                      w += (size_t)N * 16;
    f16x8* Afw  = (f16x8*)w;                       w += (size_t)NT * 64 * 16;
    f16x8* Abw  = (f16x8*)w;                       w += (size_t)NT * 64 * 16;
    f16x8* Bfw  = (f16x8*)w;                       w += (size_t)NT * 64 * 16;
    f16x8* Bbw  = (f16x8*)w;                       w += (size_t)NT * 64 * 16;
    float* Pfw  = (float*)w;                       w += (size_t)NSEG * N * 4;
    float* Pbw  = (float*)w;

    int pack_threads = 4 * NT * 64;
    if (pack_threads < N) pack_threads = N;
    pack_kernel<<<(pack_threads + 255) / 256, 256, 0, stream>>>(
        fw, bwv, p0, p1, qfw, qbw, Afw, Abw, Bfw, Bbw, out, N, NT);

    dim3 grid(ncol / WPB, NSEG, 2);
    chamfer_mfma_kernel<<<grid, 64 * WPB, 0, stream>>>(
        Afw, Bfw, Pfw, Abw, Bbw, Pbw, N, tilesPerSeg);

    dim3 rgrid((N + 255) / 256, 1, 2);
    reduce_kernel<<<rgrid, 256, 0, stream>>>(qfw, Pfw, qbw, Pbw, out, N, 1.0f / N);
}

// Round 4
// 39.812 us; speedup vs baseline: 2.7667x; 1.0057x over previous
//
#include <hip/hip_runtime.h>

typedef _Float16 f16x8 __attribute__((ext_vector_type(8)));
typedef float f32x16 __attribute__((ext_vector_type(16)));

#define TRUNC_VAL 2.0f
#define TPS 16     // A-tiles per segment (LDS-resident); NSEG = NT/TPS
#define NSEG 32    // segments for N=16384 (kept hard like prior rounds)
#define WPB 4      // waves per block
#define BPT 8      // query (B) tiles per wave: 8 MFMAs per A-frag read

// ---------------------------------------------------------------------------
// 2-kernel structure (R4): pack_kernel is FUSED into the chamfer kernel.
// R2 lesson: no device-scope fences / cross-block elections — they cost 3x
// more than a kernel boundary. R3 lesson: the MFMA-loop work is ~10us; the
// binding term is per-launch overhead (~10us each), so cut launches 3 -> 2.
//
// Fragment layout (identical values to the verified pack_kernel, absmax 0.0):
//   v_mfma_f32_32x32x16_f16, lane l of tile t at frag[t*64+l],
//   row/col = l&31, k = 8*(l>>5)+i.  hi/lo fp16 split, ~22-bit precision:
//   A (target j): [xh yh zh | xh yh zh | xl yl zl | wh wl | 0...] w=-0.5||y||^2
//   B (query  i): [xh yh zh | xl yl zl | xh yh zh | 1  1  | 0...]
//   => dot = q.y - 0.5||y||^2
// ---------------------------------------------------------------------------
__global__ __launch_bounds__(64 * WPB) void chamfer_mfma_kernel(
    const float* __restrict__ fw, const float* __restrict__ bwv,
    const float* __restrict__ p0, const float* __restrict__ p1,
    float* __restrict__ Pfw, float* __restrict__ Pbw,
    float* __restrict__ out, int N) {
    __shared__ f16x8 Alds[TPS * 64];           // 16 KB: the block's A segment

    int lane = threadIdx.x & 63;
    int wave = threadIdx.x >> 6;
    int r    = lane & 31;
    bool hi  = lane >= 32;
    int col  = blockIdx.x * WPB + wave;        // query column: 256 queries/wave
    int seg  = blockIdx.y;                     // target segment (block-shared)
    int z    = blockIdx.z;
    float* __restrict__ P = z ? Pbw : Pfw;

    // out[0] = 0 once per launch; stream-ordered before reduce's atomicAdds.
    if (threadIdx.x == 0 && blockIdx.x == 0 && blockIdx.y == 0 && z == 0)
        out[0] = 0.0f;

    // ---- build B fragments in registers (once per wave) ----
    f16x8 b[BPT];
    #pragma unroll
    for (int c = 0; c < BPT; ++c) {
        int i = (col * BPT + c) * 32 + r;
        float qx = p0[3*i]   + fw[3*i];
        float qy = p0[3*i+1] + fw[3*i+1];
        float qz = p0[3*i+2] + fw[3*i+2];
        if (z) { qx -= bwv[3*i]; qy -= bwv[3*i+1]; qz -= bwv[3*i+2]; }
        _Float16 xh = (_Float16)qx, yh = (_Float16)qy, zh = (_Float16)qz;
        _Float16 xl = (_Float16)(qx - (float)xh);
        _Float16 yl = (_Float16)(qy - (float)yh);
        _Float16 zl = (_Float16)(qz - (float)zh);
        f16x8 o;
        if (!hi) { o[0]=xh; o[1]=yh; o[2]=zh; o[3]=xl; o[4]=yl; o[5]=zl; o[6]=xh; o[7]=yh; }
        else {
            o[0]=zh; o[1]=(_Float16)1.0f; o[2]=(_Float16)1.0f;
            o[3]=(_Float16)0.0f; o[4]=(_Float16)0.0f; o[5]=(_Float16)0.0f;
            o[6]=(_Float16)0.0f; o[7]=(_Float16)0.0f;
        }
        b[c] = o;
    }

    // ---- build A fragments into LDS (each wave packs TPS/WPB = 4 tiles) ----
    const float* __restrict__ tgt = z ? p0 : p1;
    #pragma unroll
    for (int lt = 0; lt < TPS / WPB; ++lt) {
        int t = wave * (TPS / WPB) + lt;
        int j = (seg * TPS + t) * 32 + r;
        float x = tgt[3*j], y = tgt[3*j+1], zc = tgt[3*j+2];
        _Float16 xh = (_Float16)x, yh = (_Float16)y, zh = (_Float16)zc;
        _Float16 xl = (_Float16)(x  - (float)xh);
        _Float16 yl = (_Float16)(y  - (float)yh);
        _Float16 zl = (_Float16)(zc - (float)zh);
        float w = -0.5f * (x*x + y*y + zc*zc);
        _Float16 wh = (_Float16)w, wl = (_Float16)(w - (float)wh);
        f16x8 o;
        if (!hi) { o[0]=xh; o[1]=yh; o[2]=zh; o[3]=xh; o[4]=yh; o[5]=zh; o[6]=xl; o[7]=yl; }
        else {
            o[0]=zl; o[1]=wh; o[2]=wl;
            o[3]=(_Float16)0.0f; o[4]=(_Float16)0.0f; o[5]=(_Float16)0.0f;
            o[6]=(_Float16)0.0f; o[7]=(_Float16)0.0f;
        }
        Alds[t * 64 + lane] = o;
    }
    __syncthreads();

    // ---- MFMA loop: per A-tile 1 LDS frag read + 8 MFMAs + folds ----
    float m[BPT][4];
    #pragma unroll
    for (int c = 0; c < BPT; ++c)
        #pragma unroll
        for (int p = 0; p < 4; ++p) m[c][p] = -3.0e38f;

    const f32x16 zero = {};
    f16x8 a = Alds[lane];
    for (int t = 0; t < TPS; ++t) {
        f16x8 a_cur = a;
        int tn = (t + 1 < TPS) ? t + 1 : t;
        a = Alds[tn * 64 + lane];              // prefetch next A-frag
        #pragma unroll
        for (int c = 0; c < BPT; ++c) {
            f32x16 d = __builtin_amdgcn_mfma_f32_32x32x16_f16(a_cur, b[c], zero, 0, 0, 0);
            #pragma unroll
            for (int p = 0; p < 4; ++p) {
                m[c][p] = fmaxf(fmaxf(m[c][p], d[4*p  ]), d[4*p+1]);   // v_max3
                m[c][p] = fmaxf(fmaxf(m[c][p], d[4*p+2]), d[4*p+3]);   // v_max3
            }
        }
    }

    #pragma unroll
    for (int c = 0; c < BPT; ++c) {
        float v = fmaxf(fmaxf(m[c][0], m[c][1]), fmaxf(m[c][2], m[c][3]));
        v = fmaxf(v, __shfl_xor(v, 32, 64));   // fold the two row-halves
        if (lane < 32) P[(size_t)seg * N + col * (32 * BPT) + c * 32 + lane] = v;
    }
}

// ---------------------------------------------------------------------------
// Combine segment maxima, form truncated chamfer per query, mean-reduce.
// q and ||q||^2 computed inline from raw inputs (bit-matches the old pack's
// values — proven by R2's absmax 0.0 with this exact expression).
// ---------------------------------------------------------------------------
__global__ __launch_bounds__(256) void reduce_kernel(
    const float* __restrict__ fw, const float* __restrict__ bwv,
    const float* __restrict__ p0,
    const float* __restrict__ Pfw, const float* __restrict__ Pbw,
    float* __restrict__ out, int N, float inv) {
    int z = blockIdx.z;
    const float* __restrict__ part = z ? Pbw : Pfw;

    int i = blockIdx.x * blockDim.x + threadIdx.x;
    float c = 0.0f;
    if (i < N) {
        float qx = p0[3*i]   + fw[3*i];
        float qy = p0[3*i+1] + fw[3*i+1];
        float qz = p0[3*i+2] + fw[3*i+2];
        if (z) { qx -= bwv[3*i]; qy -= bwv[3*i+1]; qz -= bwv[3*i+2]; }
        float q2 = qx*qx + qy*qy + qz*qz;
        float mv = -3.0e38f;
        #pragma unroll
        for (int s = 0; s < NSEG; ++s) mv = fmaxf(mv, part[(size_t)s * N + i]);
        float d2 = fmaf(-2.0f, mv, q2);        // ||q||^2 - 2*max = min sq dist
        d2 = fmaxf(d2, 0.0f);
        c = fminf(d2, TRUNC_VAL);
    }
    #pragma unroll
    for (int off = 32; off > 0; off >>= 1) c += __shfl_down(c, off, 64);
    __shared__ float wsum[256 / 64];
    int lane = threadIdx.x & 63, wid = threadIdx.x >> 6;
    if (lane == 0) wsum[wid] = c;
    __syncthreads();
    if (threadIdx.x == 0) {
        float s = 0.0f;
        #pragma unroll
        for (int w = 0; w < 256 / 64; ++w) s += wsum[w];
        atomicAdd(out, s * inv);
    }
}

extern "C" void kernel_launch(void* const* d_in, const int* in_sizes, int n_in,
                              void* d_out, int out_size, void* d_ws, size_t ws_size,
                              hipStream_t stream) {
    const float* fw  = (const float*)d_in[0];  // fw_flow_pred [N,3]
    const float* bwv = (const float*)d_in[1];  // bw_flow_pred [N,3]
    const float* p0  = (const float*)d_in[2];  // pcl_0 [N,3]
    const float* p1  = (const float*)d_in[3];  // pcl_1 [M,3]
    int N = in_sizes[0] / 3;                   // 16384; M == N for this problem
    int ncol = N / (32 * BPT);                 // 64 query columns

    float* out = (float*)d_out;
    char* w = (char*)d_ws;
    float* Pfw = (float*)w;                    w += (size_t)NSEG * N * 4;
    float* Pbw = (float*)w;

    dim3 grid(ncol / WPB, NSEG, 2);            // (16, 32, 2) = 1024 blocks
    chamfer_mfma_kernel<<<grid, 64 * WPB, 0, stream>>>(
        fw, bwv, p0, p1, Pfw, Pbw, out, N);

    dim3 rgrid((N + 255) / 256, 1, 2);
    reduce_kernel<<<rgrid, 256, 0, stream>>>(
        fw, bwv, p0, Pfw, Pbw, out, N, 1.0f / N);
}

// Round 5
// 30.739 us; speedup vs baseline: 3.5834x; 1.2952x over previous
//
#include <hip/hip_runtime.h>

typedef _Float16 f16x8 __attribute__((ext_vector_type(8)));
typedef float f32x16 __attribute__((ext_vector_type(16)));

#define TRUNC_VAL 2.0f
#define TPS 16     // A-tiles per segment (LDS-resident); NSEG = NT/TPS
#define NSEG 32    // segments for N=16384
#define WPB 4      // waves per block
#define BPT 8      // query (B) tiles per wave: 8 MFMAs per A-frag read

// ---------------------------------------------------------------------------
// R5: same 2-kernel structure as R4 (absmax 0.0). Only change: the MFMA
// inner loop issues 4 independent MFMAs into 4 named accumulators before
// folding (breaks the MFMA->fold serialization the compiler produced at
// 88 VGPRs), and __launch_bounds__(256,2) raises the register budget.
// R2 lesson: no device-scope fences. R3/R4 lesson: launches aren't the
// binding term; the chamfer kernel's stalled schedule is (VALUBusy 55%,
// MfmaUtil 15%, VALU-busy 23us vs ~7us of real fold work).
//
// Fragment layout (identical values to the verified pack, absmax 0.0):
//   v_mfma_f32_32x32x16_f16, lane l of tile t at frag[t*64+l],
//   row/col = l&31, k = 8*(l>>5)+i.  hi/lo fp16 split, ~22-bit precision:
//   A (target j): [xh yh zh | xh yh zh | xl yl zl | wh wl | 0...] w=-0.5||y||^2
//   B (query  i): [xh yh zh | xl yl zl | xh yh zh | 1  1  | 0...]
//   => dot = q.y - 0.5||y||^2
// ---------------------------------------------------------------------------
__global__ __launch_bounds__(64 * WPB, 2) void chamfer_mfma_kernel(
    const float* __restrict__ fw, const float* __restrict__ bwv,
    const float* __restrict__ p0, const float* __restrict__ p1,
    float* __restrict__ Pfw, float* __restrict__ Pbw,
    float* __restrict__ out, int N) {
    __shared__ f16x8 Alds[TPS * 64];           // 16 KB: the block's A segment

    int lane = threadIdx.x & 63;
    int wave = threadIdx.x >> 6;
    int r    = lane & 31;
    bool hi  = lane >= 32;
    int col  = blockIdx.x * WPB + wave;        // query column: 256 queries/wave
    int seg  = blockIdx.y;                     // target segment (block-shared)
    int z    = blockIdx.z;
    float* __restrict__ P = z ? Pbw : Pfw;

    // out[0] = 0 once per launch; stream-ordered before reduce's atomicAdds.
    if (threadIdx.x == 0 && blockIdx.x == 0 && blockIdx.y == 0 && z == 0)
        out[0] = 0.0f;

    // ---- build B fragments in registers (once per wave) ----
    f16x8 b[BPT];
    #pragma unroll
    for (int c = 0; c < BPT; ++c) {
        int i = (col * BPT + c) * 32 + r;
        float qx = p0[3*i]   + fw[3*i];
        float qy = p0[3*i+1] + fw[3*i+1];
        float qz = p0[3*i+2] + fw[3*i+2];
        if (z) { qx -= bwv[3*i]; qy -= bwv[3*i+1]; qz -= bwv[3*i+2]; }
        _Float16 xh = (_Float16)qx, yh = (_Float16)qy, zh = (_Float16)qz;
        _Float16 xl = (_Float16)(qx - (float)xh);
        _Float16 yl = (_Float16)(qy - (float)yh);
        _Float16 zl = (_Float16)(qz - (float)zh);
        f16x8 o;
        if (!hi) { o[0]=xh; o[1]=yh; o[2]=zh; o[3]=xl; o[4]=yl; o[5]=zl; o[6]=xh; o[7]=yh; }
        else {
            o[0]=zh; o[1]=(_Float16)1.0f; o[2]=(_Float16)1.0f;
            o[3]=(_Float16)0.0f; o[4]=(_Float16)0.0f; o[5]=(_Float16)0.0f;
            o[6]=(_Float16)0.0f; o[7]=(_Float16)0.0f;
        }
        b[c] = o;
    }

    // ---- build A fragments into LDS (each wave packs TPS/WPB = 4 tiles) ----
    const float* __restrict__ tgt = z ? p0 : p1;
    #pragma unroll
    for (int lt = 0; lt < TPS / WPB; ++lt) {
        int t = wave * (TPS / WPB) + lt;
        int j = (seg * TPS + t) * 32 + r;
        float x = tgt[3*j], y = tgt[3*j+1], zc = tgt[3*j+2];
        _Float16 xh = (_Float16)x, yh = (_Float16)y, zh = (_Float16)zc;
        _Float16 xl = (_Float16)(x  - (float)xh);
        _Float16 yl = (_Float16)(y  - (float)yh);
        _Float16 zl = (_Float16)(zc - (float)zh);
        float w = -0.5f * (x*x + y*y + zc*zc);
        _Float16 wh = (_Float16)w, wl = (_Float16)(w - (float)wh);
        f16x8 o;
        if (!hi) { o[0]=xh; o[1]=yh; o[2]=zh; o[3]=xh; o[4]=yh; o[5]=zh; o[6]=xl; o[7]=yl; }
        else {
            o[0]=zl; o[1]=wh; o[2]=wl;
            o[3]=(_Float16)0.0f; o[4]=(_Float16)0.0f; o[5]=(_Float16)0.0f;
            o[6]=(_Float16)0.0f; o[7]=(_Float16)0.0f;
        }
        Alds[t * 64 + lane] = o;
    }
    __syncthreads();

    // ---- MFMA loop: groups of 4 independent MFMAs, then fold ----
    float m[BPT][4];
    #pragma unroll
    for (int c = 0; c < BPT; ++c)
        #pragma unroll
        for (int p = 0; p < 4; ++p) m[c][p] = -3.0e38f;

    const f32x16 zero = {};
    f16x8 a = Alds[lane];

#define FOLD(c, d)                                                  \
    _Pragma("unroll")                                               \
    for (int p = 0; p < 4; ++p) {                                   \
        m[c][p] = fmaxf(fmaxf(m[c][p], d[4*p  ]), d[4*p+1]);        \
        m[c][p] = fmaxf(fmaxf(m[c][p], d[4*p+2]), d[4*p+3]);        \
    }

    for (int t = 0; t < TPS; ++t) {
        f16x8 a_cur = a;
        int tn = (t + 1 < TPS) ? t + 1 : t;
        a = Alds[tn * 64 + lane];              // prefetch next A-frag
        // group 0: 4 MFMAs in flight before any fold touches their results
        f32x16 d0 = __builtin_amdgcn_mfma_f32_32x32x16_f16(a_cur, b[0], zero, 0, 0, 0);
        f32x16 d1 = __builtin_amdgcn_mfma_f32_32x32x16_f16(a_cur, b[1], zero, 0, 0, 0);
        f32x16 d2 = __builtin_amdgcn_mfma_f32_32x32x16_f16(a_cur, b[2], zero, 0, 0, 0);
        f32x16 d3 = __builtin_amdgcn_mfma_f32_32x32x16_f16(a_cur, b[3], zero, 0, 0, 0);
        FOLD(0, d0) FOLD(1, d1) FOLD(2, d2) FOLD(3, d3)
        // group 1
        f32x16 d4 = __builtin_amdgcn_mfma_f32_32x32x16_f16(a_cur, b[4], zero, 0, 0, 0);
        f32x16 d5 = __builtin_amdgcn_mfma_f32_32x32x16_f16(a_cur, b[5], zero, 0, 0, 0);
        f32x16 d6 = __builtin_amdgcn_mfma_f32_32x32x16_f16(a_cur, b[6], zero, 0, 0, 0);
        f32x16 d7 = __builtin_amdgcn_mfma_f32_32x32x16_f16(a_cur, b[7], zero, 0, 0, 0);
        FOLD(4, d4) FOLD(5, d5) FOLD(6, d6) FOLD(7, d7)
    }
#undef FOLD

    #pragma unroll
    for (int c = 0; c < BPT; ++c) {
        float v = fmaxf(fmaxf(m[c][0], m[c][1]), fmaxf(m[c][2], m[c][3]));
        v = fmaxf(v, __shfl_xor(v, 32, 64));   // fold the two row-halves
        if (lane < 32) P[(size_t)seg * N + col * (32 * BPT) + c * 32 + lane] = v;
    }
}

// ---------------------------------------------------------------------------
// Combine segment maxima, form truncated chamfer per query, mean-reduce.
// (identical to R4 — absmax 0.0)
// ---------------------------------------------------------------------------
__global__ __launch_bounds__(256) void reduce_kernel(
    const float* __restrict__ fw, const float* __restrict__ bwv,
    const float* __restrict__ p0,
    const float* __restrict__ Pfw, const float* __restrict__ Pbw,
    float* __restrict__ out, int N, float inv) {
    int z = blockIdx.z;
    const float* __restrict__ part = z ? Pbw : Pfw;

    int i = blockIdx.x * blockDim.x + threadIdx.x;
    float c = 0.0f;
    if (i < N) {
        float qx = p0[3*i]   + fw[3*i];
        float qy = p0[3*i+1] + fw[3*i+1];
        float qz = p0[3*i+2] + fw[3*i+2];
        if (z) { qx -= bwv[3*i]; qy -= bwv[3*i+1]; qz -= bwv[3*i+2]; }
        float q2 = qx*qx + qy*qy + qz*qz;
        float mv = -3.0e38f;
        #pragma unroll
        for (int s = 0; s < NSEG; ++s) mv = fmaxf(mv, part[(size_t)s * N + i]);
        float d2 = fmaf(-2.0f, mv, q2);        // ||q||^2 - 2*max = min sq dist
        d2 = fmaxf(d2, 0.0f);
        c = fminf(d2, TRUNC_VAL);
    }
    #pragma unroll
    for (int off = 32; off > 0; off >>= 1) c += __shfl_down(c, off, 64);
    __shared__ float wsum[256 / 64];
    int lane = threadIdx.x & 63, wid = threadIdx.x >> 6;
    if (lane == 0) wsum[wid] = c;
    __syncthreads();
    if (threadIdx.x == 0) {
        float s = 0.0f;
        #pragma unroll
        for (int w = 0; w < 256 / 64; ++w) s += wsum[w];
        atomicAdd(out, s * inv);
    }
}

extern "C" void kernel_launch(void* const* d_in, const int* in_sizes, int n_in,
                              void* d_out, int out_size, void* d_ws, size_t ws_size,
                              hipStream_t stream) {
    const float* fw  = (const float*)d_in[0];  // fw_flow_pred [N,3]
    const float* bwv = (const float*)d_in[1];  // bw_flow_pred [N,3]
    const float* p0  = (const float*)d_in[2];  // pcl_0 [N,3]
    const float* p1  = (const float*)d_in[3];  // pcl_1 [M,3]
    int N = in_sizes[0] / 3;                   // 16384; M == N for this problem
    int ncol = N / (32 * BPT);                 // 64 query columns

    float* out = (float*)d_out;
    char* w = (char*)d_ws;
    float* Pfw = (float*)w;                    w += (size_t)NSEG * N * 4;
    float* Pbw = (float*)w;

    dim3 grid(ncol / WPB, NSEG, 2);            // (16, 32, 2) = 1024 blocks
    chamfer_mfma_kernel<<<grid, 64 * WPB, 0, stream>>>(
        fw, bwv, p0, p1, Pfw, Pbw, out, N);

    dim3 rgrid((N + 255) / 256, 1, 2);
    reduce_kernel<<<rgrid, 256, 0, stream>>>(
        fw, bwv, p0, Pfw, Pbw, out, N, 1.0f / N);
}